// Round 1
// baseline (663.984 us; speedup 1.0000x reference)
//
#include <hip/hip_runtime.h>
#include <math.h>

// Problem constants (GaussianVQ: bs=64, dim_z=64, W=H=32, K=1024)
#define K_CB    1024
#define D_Z     64
#define M_TILE  16
#define N_TOTAL 65536            // bs*W*H
#define NBLK    (N_TOTAL / M_TILE)   // 4096

// ws layout (floats):
//   [0]           w = 0.5/clip(exp(0)+exp(lvq),1e-10)
//   [16..16+1024) sq_c[k]
//   [2048..+65536) cT[d][k]  (codebook transposed, 64x1024)
//   [67584..+4096) per-block kld partials
// total = 286,720 bytes
#define WS_W    0
#define WS_SQC  16
#define WS_CT   2048
#define WS_PART (2048 + 65536)

__global__ void vq_prep(const float* __restrict__ cb,
                        const float* __restrict__ lvq,
                        float* __restrict__ ws) {
  const int b = blockIdx.x, t = threadIdx.x;
  if (b == 64) {
    #pragma unroll
    for (int i = 0; i < 4; i++) {
      const int k = t * 4 + i;
      const float* row = cb + k * D_Z;
      float s = 0.f;
      for (int d = 0; d < D_Z; d++) s = fmaf(row[d], row[d], s);
      ws[WS_SQC + k] = s;
    }
    if (t == 0) {
      float var_q = 1.0f + expf(lvq[0]);   // exp(LOG_VAR_Q=0)=1
      var_q = fmaxf(var_q, 1e-10f);
      ws[WS_W] = 0.5f / var_q;
    }
  } else {
    const int d = b;  // 0..63
    for (int k = t; k < K_CB; k += 256)
      ws[WS_CT + d * K_CB + k] = cb[k * D_Z + d];
  }
}

__global__ __launch_bounds__(256)
void vq_main(const float* __restrict__ x,
             const float* __restrict__ cb,
             const float* __restrict__ gum,
             float* __restrict__ ws,
             float* __restrict__ out) {
  __shared__ float xs[M_TILE][68];        // x tile, padded
  __shared__ float sqc_s[K_CB];
  __shared__ float es[M_TILE][1028];      // encodings, padded stride
  __shared__ float sqx_s[M_TILE];
  __shared__ float wred[4];

  const int tid  = threadIdx.x;
  const int blk  = blockIdx.x;
  const int row0 = blk * M_TILE;
  const int bidx = row0 >> 10;            // batch index (W*H=1024)
  const int rem0 = row0 & 1023;
  const int wv   = tid >> 6;              // wave 0..3, owns rows 4wv..4wv+3
  const int lane = tid & 63;

  const float w = ws[WS_W];

  // ---- P0: load x tile (coalesced: consecutive tid -> consecutive rem) ----
  {
    const int m = tid & 15, dbase = tid >> 4;
    #pragma unroll
    for (int i = 0; i < 4; i++) {
      const int d = dbase + 16 * i;
      xs[m][d] = x[((bidx * D_Z + d) << 10) + rem0 + m];
    }
  }
  for (int k = tid; k < K_CB; k += 256) sqc_s[k] = ws[WS_SQC + k];
  __syncthreads();
  if (tid < M_TILE) {
    float s = 0.f;
    #pragma unroll
    for (int d = 0; d < D_Z; d++) s = fmaf(xs[tid][d], xs[tid][d], s);
    sqx_s[tid] = s;
  }
  __syncthreads();

  // ---- P1: GEMM1 cross[m][k]; lane owns k = lane + 64*t ----
  float acc[4][16];
  #pragma unroll
  for (int r = 0; r < 4; r++)
    #pragma unroll
    for (int t = 0; t < 16; t++) acc[r][t] = 0.f;

  {
    const float* ctp = ws + WS_CT + lane;
    for (int d4 = 0; d4 < 16; d4++) {
      float xvf[4][4];
      #pragma unroll
      for (int r = 0; r < 4; r++) {
        const float4 v = *(const float4*)&xs[4 * wv + r][4 * d4];
        xvf[r][0] = v.x; xvf[r][1] = v.y; xvf[r][2] = v.z; xvf[r][3] = v.w;
      }
      #pragma unroll
      for (int dd = 0; dd < 4; dd++) {
        const float* cr = ctp + (4 * d4 + dd) * K_CB;
        #pragma unroll
        for (int t = 0; t < 16; t++) {
          const float cv = cr[64 * t];
          acc[0][t] = fmaf(cv, xvf[0][dd], acc[0][t]);
          acc[1][t] = fmaf(cv, xvf[1][dd], acc[1][t]);
          acc[2][t] = fmaf(cv, xvf[2][dd], acc[2][t]);
          acc[3][t] = fmaf(cv, xvf[3][dd], acc[3][t]);
        }
      }
    }
  }

  // logits: acc = w*(2*cross - sqx - sqc)
  {
    const float w2 = 2.0f * w;
    float base[4];
    #pragma unroll
    for (int r = 0; r < 4; r++) base[r] = -w * sqx_s[4 * wv + r];
    #pragma unroll
    for (int t = 0; t < 16; t++) {
      const float sc = -w * sqc_s[lane + 64 * t];
      #pragma unroll
      for (int r = 0; r < 4; r++)
        acc[r][t] = fmaf(w2, acc[r][t], base[r] + sc);
    }
  }

  // ---- P2: softmax stats + encodings (gumbel read exactly once) ----
  float kacc = 0.f;
  #pragma unroll
  for (int r = 0; r < 4; r++) {
    const int row = row0 + 4 * wv + r;
    const float* gp = gum + row * K_CB + lane;
    float g[16];
    #pragma unroll
    for (int t = 0; t < 16; t++) g[t] = gp[64 * t];
    #pragma unroll
    for (int t = 0; t < 16; t++) g[t] = 2.0f * (acc[r][t] + g[t]); // (logit+g)/T, T=0.5
    float m1 = acc[r][0], m2 = g[0];
    #pragma unroll
    for (int t = 1; t < 16; t++) { m1 = fmaxf(m1, acc[r][t]); m2 = fmaxf(m2, g[t]); }
    #pragma unroll
    for (int off = 32; off > 0; off >>= 1) {
      m1 = fmaxf(m1, __shfl_xor(m1, off));
      m2 = fmaxf(m2, __shfl_xor(m2, off));
    }
    float s1 = 0.f, A = 0.f, s2 = 0.f;
    #pragma unroll
    for (int t = 0; t < 16; t++) {
      const float u = acc[r][t] - m1;
      const float e = __expf(u);
      s1 += e;
      A = fmaf(u, e, A);
      const float e2 = __expf(g[t] - m2);
      g[t] = e2;
      s2 += e2;
    }
    #pragma unroll
    for (int off = 32; off > 0; off >>= 1) {
      s1 += __shfl_xor(s1, off);
      A  += __shfl_xor(A,  off);
      s2 += __shfl_xor(s2, off);
    }
    const float inv2 = 1.0f / s2;
    #pragma unroll
    for (int t = 0; t < 16; t++)
      es[4 * wv + r][lane + 64 * t] = g[t] * inv2;
    // sum(p*logp) for this row = A/s1 - log(s1)
    if (lane == 0) kacc += A / s1 - __logf(s1);
  }
  __syncthreads();

  // ---- P3: GEMM2 quantized[m][d] = sum_k enc[m][k]*c[k][d] ----
  const int m  = tid & 15;       // row within tile (write-coalescing order)
  const int dq = tid >> 4;       // d-quad 0..15
  float q0 = 0.f, q1 = 0.f, q2 = 0.f, q3 = 0.f;
  {
    const float* cbp = cb + 4 * dq;
    for (int k = 0; k < K_CB; k += 4) {
      const float4 e4 = *(const float4*)&es[m][k];
      const float4 c0 = *(const float4*)(cbp + (k + 0) * D_Z);
      const float4 c1 = *(const float4*)(cbp + (k + 1) * D_Z);
      const float4 c2 = *(const float4*)(cbp + (k + 2) * D_Z);
      const float4 c3 = *(const float4*)(cbp + (k + 3) * D_Z);
      q0 = fmaf(e4.x, c0.x, q0); q1 = fmaf(e4.x, c0.y, q1);
      q2 = fmaf(e4.x, c0.z, q2); q3 = fmaf(e4.x, c0.w, q3);
      q0 = fmaf(e4.y, c1.x, q0); q1 = fmaf(e4.y, c1.y, q1);
      q2 = fmaf(e4.y, c1.z, q2); q3 = fmaf(e4.y, c1.w, q3);
      q0 = fmaf(e4.z, c2.x, q0); q1 = fmaf(e4.z, c2.y, q1);
      q2 = fmaf(e4.z, c2.z, q2); q3 = fmaf(e4.z, c2.w, q3);
      q0 = fmaf(e4.w, c3.x, q0); q1 = fmaf(e4.w, c3.y, q1);
      q2 = fmaf(e4.w, c3.z, q2); q3 = fmaf(e4.w, c3.w, q3);
    }
  }

  // ---- P4: write quantized (transposed) + kld_continuous ----
  float kc = 0.f;
  {
    float qa[4] = {q0, q1, q2, q3};
    #pragma unroll
    for (int i = 0; i < 4; i++) {
      const int d = 4 * dq + i;
      out[((bidx * D_Z + d) << 10) + rem0 + m] = qa[i];
      const float dx = xs[m][d] - qa[i];
      kc = fmaf(w * dx, dx, kc);
    }
  }
  float val = kacc + kc;
  #pragma unroll
  for (int off = 32; off > 0; off >>= 1) val += __shfl_xor(val, off);
  if (lane == 0) wred[wv] = val;
  __syncthreads();
  if (tid == 0) ws[WS_PART + blk] = wred[0] + wred[1] + wred[2] + wred[3];
}

__global__ void vq_reduce(const float* __restrict__ ws, float* __restrict__ out) {
  __shared__ float red[256];
  const int t = threadIdx.x;
  float s = 0.f;
  for (int i = t; i < NBLK; i += 256) s += ws[WS_PART + i];
  red[t] = s;
  __syncthreads();
  for (int st = 128; st > 0; st >>= 1) {
    if (t < st) red[t] += red[t + st];
    __syncthreads();
  }
  if (t == 0) out[N_TOTAL * D_Z] = red[0] * (1.0f / 64.0f);  // /bs
}

extern "C" void kernel_launch(void* const* d_in, const int* in_sizes, int n_in,
                              void* d_out, int out_size, void* d_ws, size_t ws_size,
                              hipStream_t stream) {
  const float* x   = (const float*)d_in[0];
  const float* cb  = (const float*)d_in[1];
  const float* lvq = (const float*)d_in[2];
  const float* gum = (const float*)d_in[3];
  float* out = (float*)d_out;
  float* ws  = (float*)d_ws;

  hipLaunchKernelGGL(vq_prep,   dim3(65),   dim3(256), 0, stream, cb, lvq, ws);
  hipLaunchKernelGGL(vq_main,   dim3(NBLK), dim3(256), 0, stream, x, cb, gum, ws, out);
  hipLaunchKernelGGL(vq_reduce, dim3(1),    dim3(256), 0, stream, ws, out);
}

// Round 2
// 179.080 us; speedup vs baseline: 3.7078x; 3.7078x over previous
//
#include <hip/hip_runtime.h>
#include <math.h>

#define K_CB 1024
#define D_Z  64
#define MT   16
#define NTOT 65536
#define NBLK (NTOT / MT)

typedef __attribute__((ext_vector_type(8))) short  s16x8;
typedef __attribute__((ext_vector_type(4))) short  s16x4;
typedef __attribute__((ext_vector_type(4))) float  f32x4;

// ws layout (bytes)
#define WS_CB16  0        // [1024][64] bf16  = 131072
#define WS_CBT16 131072   // [64][1024] bf16  = 131072
#define WS_NWSQC 262144   // [1024] f32 (-w*||c||^2) = 4096
#define WS_PART  266240   // [4096] f32 block partials

__device__ __forceinline__ unsigned short f2b(float f) {
  unsigned int u = __float_as_uint(f);
  u += 0x7fffu + ((u >> 16) & 1u);
  return (unsigned short)(u >> 16);
}

__global__ void vq_prep(const float* __restrict__ cb, const float* __restrict__ lvq,
                        unsigned char* __restrict__ wsb) {
  unsigned short* cb16  = (unsigned short*)(wsb + WS_CB16);
  unsigned short* cbT16 = (unsigned short*)(wsb + WS_CBT16);
  float* nwsqc = (float*)(wsb + WS_NWSQC);
  const float w = 0.5f / fmaxf(1.0f + __expf(lvq[0]), 1e-10f);
  const int tid = threadIdx.x;
  const int k  = blockIdx.x * 16 + (tid >> 4);
  const int d0 = (tid & 15) * 4;
  const f32x4 v = *(const f32x4*)(cb + k * D_Z + d0);
  s16x4 b4;
  #pragma unroll
  for (int i = 0; i < 4; i++) b4[i] = (short)f2b(v[i]);
  *(s16x4*)(cb16 + k * D_Z + d0) = b4;
  #pragma unroll
  for (int i = 0; i < 4; i++) cbT16[(d0 + i) * K_CB + k] = (unsigned short)b4[i];
  float s = v[0]*v[0] + v[1]*v[1] + v[2]*v[2] + v[3]*v[3];
  #pragma unroll
  for (int off = 1; off < 16; off <<= 1) s += __shfl_xor(s, off);
  if ((tid & 15) == 0) nwsqc[k] = -w * s;
}

__global__ __launch_bounds__(256, 3)
void vq_main(const float* __restrict__ x, const float* __restrict__ gum,
             const float* __restrict__ lvq, unsigned char* __restrict__ wsb,
             float* __restrict__ out) {
  __shared__ __align__(16) unsigned short xa[1024];      // x bf16, frag-linear [c][g][m][8]
  __shared__ __align__(16) float xs[MT][68];             // x f32 (for kld_continuous)
  __shared__ __align__(16) float sqcs[K_CB];             // -w*||c||^2
  __shared__ __align__(16) unsigned short es[MT][1032];  // encodings bf16, padded stride
  __shared__ __align__(16) float pstat[4][MT][4];        // per-wave m1,s1,A,m2
  __shared__ __align__(16) float s2p[4][MT];
  __shared__ float kldrow[MT];
  __shared__ float wred[4];

  const int tid  = threadIdx.x;
  const int wv   = tid >> 6;
  const int lane = tid & 63;
  const int m16  = lane & 15;   // MFMA col = row-in-tile
  const int g    = lane >> 4;

  const int blk  = blockIdx.x;
  const int row0 = blk * MT;
  const int bidx = row0 >> 10;
  const int rem0 = row0 & 1023;

  const float w  = 0.5f / fmaxf(1.0f + __expf(lvq[0]), 1e-10f);
  const float w2 = 2.0f * w;

  const unsigned short* cb16  = (const unsigned short*)(wsb + WS_CB16);
  const unsigned short* cbT16 = (const unsigned short*)(wsb + WS_CBT16);
  const float* nwsqc = (const float*)(wsb + WS_NWSQC);

  // ---- P0: stage x tile (bf16 frag layout + f32 copy) and sqc ----
  {
    const int m = tid & 15, db = tid >> 4;
    #pragma unroll
    for (int i = 0; i < 4; i++) {
      const int d = db + 16 * i;
      const float v = x[((bidx * D_Z + d) << 10) + rem0 + m];
      xs[m][d] = v;
      xa[(d >> 5) * 512 + ((d >> 3) & 3) * 128 + m * 8 + (d & 7)] = f2b(v);
    }
    for (int k = tid; k < K_CB; k += 256) sqcs[k] = nwsqc[k];
  }
  __syncthreads();

  // ---- P1: GEMM1 (swapped): D[code][m] = cb . x^T ; wave owns codes [wv*256, +256) ----
  f32x4 acc[16];
  #pragma unroll
  for (int t = 0; t < 16; t++) acc[t] = (f32x4){0.f, 0.f, 0.f, 0.f};
  {
    const s16x8 xb0 = *(const s16x8*)(xa + g * 128 + m16 * 8);         // x[m16][g*8..+8]
    const s16x8 xb1 = *(const s16x8*)(xa + 512 + g * 128 + m16 * 8);   // x[m16][32+g*8..+8]
    const unsigned short* ap = cb16 + (wv * 256 + m16) * D_Z + g * 8;
    #pragma unroll
    for (int t = 0; t < 16; t++) {
      const s16x8 a0 = *(const s16x8*)(ap + t * 1024);        // cb[code][0..32)
      const s16x8 a1 = *(const s16x8*)(ap + t * 1024 + 32);   // cb[code][32..64)
      acc[t] = __builtin_amdgcn_mfma_f32_16x16x32_bf16(a0, xb0, acc[t], 0, 0, 0);
      acc[t] = __builtin_amdgcn_mfma_f32_16x16x32_bf16(a1, xb1, acc[t], 0, 0, 0);
    }
  }

  // ---- P2: logits (row-shifted; -w*||x||^2 cancels in softmax) + P3: p-stats ----
  float m1 = -3.4e38f;
  #pragma unroll
  for (int t = 0; t < 16; t++) {
    const f32x4 sc = *(const f32x4*)&sqcs[wv * 256 + t * 16 + g * 4];
    #pragma unroll
    for (int r = 0; r < 4; r++) {
      acc[t][r] = fmaf(w2, acc[t][r], sc[r]);
      m1 = fmaxf(m1, acc[t][r]);
    }
  }
  m1 = fmaxf(m1, __shfl_xor(m1, 16));
  m1 = fmaxf(m1, __shfl_xor(m1, 32));
  float s1 = 0.f, Aa = 0.f;
  #pragma unroll
  for (int t = 0; t < 16; t++) {
    #pragma unroll
    for (int r = 0; r < 4; r++) {
      const float u = acc[t][r] - m1;
      const float e = __expf(u);
      s1 += e;
      Aa = fmaf(u, e, Aa);
    }
  }
  s1 += __shfl_xor(s1, 16); s1 += __shfl_xor(s1, 32);
  Aa += __shfl_xor(Aa, 16); Aa += __shfl_xor(Aa, 32);

  // ---- P4: gumbel stream (read once, coalesced float4, matches reg layout) ----
  float m2 = -3.4e38f;
  const float* gp = gum + (row0 + m16) * K_CB + wv * 256 + g * 4;
  #pragma unroll
  for (int t = 0; t < 16; t++) {
    const f32x4 gv = __builtin_nontemporal_load((const f32x4*)(gp + t * 16));
    #pragma unroll
    for (int r = 0; r < 4; r++) {
      const float z = 2.0f * (acc[t][r] + gv[r]);   // (logit+g)/T, T=0.5
      acc[t][r] = z;
      m2 = fmaxf(m2, z);
    }
  }
  m2 = fmaxf(m2, __shfl_xor(m2, 16));
  m2 = fmaxf(m2, __shfl_xor(m2, 32));
  if (g == 0) {
    pstat[wv][m16][0] = m1; pstat[wv][m16][1] = s1;
    pstat[wv][m16][2] = Aa; pstat[wv][m16][3] = m2;
  }
  __syncthreads();

  // ---- P5: cross-wave merge of row stats ----
  float M2 = -3.4e38f;
  {
    float M1 = -3.4e38f;
    f32x4 pw[4];
    #pragma unroll
    for (int q = 0; q < 4; q++) {
      pw[q] = *(const f32x4*)&pstat[q][m16][0];
      M1 = fmaxf(M1, pw[q][0]);
      M2 = fmaxf(M2, pw[q][3]);
    }
    float s1g = 0.f, Ag = 0.f;
    #pragma unroll
    for (int q = 0; q < 4; q++) {
      const float dm = pw[q][0] - M1;
      const float c = __expf(dm);
      s1g += c * pw[q][1];
      Ag = fmaf(c, fmaf(dm, pw[q][1], pw[q][2]), Ag);
    }
    if (tid < 16) kldrow[m16] = Ag / s1g - __logf(s1g);  // sum p*logp for row
  }

  // ---- P6: encodings e2 = exp(z - M2), unnormalized, bf16 -> LDS ----
  float s2 = 0.f;
  #pragma unroll
  for (int t = 0; t < 16; t++) {
    s16x4 ev;
    #pragma unroll
    for (int r = 0; r < 4; r++) {
      const float e = __expf(acc[t][r] - M2);
      s2 += e;
      ev[r] = (short)f2b(e);
    }
    *(s16x4*)&es[m16][wv * 256 + t * 16 + g * 4] = ev;
  }
  s2 += __shfl_xor(s2, 16); s2 += __shfl_xor(s2, 32);
  if (g == 0) s2p[wv][m16] = s2;
  __syncthreads();

  // ---- P7/P8: GEMM2 (swapped): D[d][m] = cb^T . e2^T ; wave owns d-tile wv*16 ----
  const float inv2 = 1.0f / (s2p[0][m16] + s2p[1][m16] + s2p[2][m16] + s2p[3][m16]);
  f32x4 qacc = (f32x4){0.f, 0.f, 0.f, 0.f};
  {
    const unsigned short* a2p = cbT16 + (wv * 16 + m16) * K_CB + g * 8;
    const unsigned short* b2p = &es[m16][g * 8];
    #pragma unroll
    for (int kc = 0; kc < 32; kc++) {
      const s16x8 a2 = *(const s16x8*)(a2p + kc * 32);
      const s16x8 b2 = *(const s16x8*)(b2p + kc * 32);
      qacc = __builtin_amdgcn_mfma_f32_16x16x32_bf16(a2, b2, qacc, 0, 0, 0);
    }
  }

  // ---- P9: normalize, write quantized (d-major coalesced), kld_continuous ----
  float kca = 0.f;
  #pragma unroll
  for (int r = 0; r < 4; r++) {
    const int d = wv * 16 + g * 4 + r;
    const float qv = qacc[r] * inv2;
    __builtin_nontemporal_store(qv, out + ((bidx * D_Z + d) << 10) + rem0 + m16);
    const float dx = xs[m16][d] - qv;
    kca = fmaf(dx, dx, kca);
  }
  #pragma unroll
  for (int off = 1; off < 64; off <<= 1) kca += __shfl_xor(kca, off);
  if (lane == 0) wred[wv] = kca;
  __syncthreads();
  if (tid == 0) {
    float tot = w * (wred[0] + wred[1] + wred[2] + wred[3]);
    #pragma unroll
    for (int i = 0; i < MT; i++) tot += kldrow[i];
    ((float*)(wsb + WS_PART))[blk] = tot;
  }
}

__global__ void vq_reduce(const unsigned char* __restrict__ wsb, float* __restrict__ out) {
  __shared__ float red[256];
  const float* part = (const float*)(wsb + WS_PART);
  const int t = threadIdx.x;
  float s = 0.f;
  for (int i = t; i < NBLK; i += 256) s += part[i];
  red[t] = s;
  __syncthreads();
  for (int st = 128; st > 0; st >>= 1) {
    if (t < st) red[t] += red[t + st];
    __syncthreads();
  }
  if (t == 0) out[NTOT * D_Z] = red[0] * (1.0f / 64.0f);
}

extern "C" void kernel_launch(void* const* d_in, const int* in_sizes, int n_in,
                              void* d_out, int out_size, void* d_ws, size_t ws_size,
                              hipStream_t stream) {
  const float* x   = (const float*)d_in[0];
  const float* cb  = (const float*)d_in[1];
  const float* lvq = (const float*)d_in[2];
  const float* gum = (const float*)d_in[3];
  float* out = (float*)d_out;
  unsigned char* wsb = (unsigned char*)d_ws;

  hipLaunchKernelGGL(vq_prep,   dim3(64),   dim3(256), 0, stream, cb, lvq, wsb);
  hipLaunchKernelGGL(vq_main,   dim3(NBLK), dim3(256), 0, stream, x, gum, lvq, wsb, out);
  hipLaunchKernelGGL(vq_reduce, dim3(1),    dim3(256), 0, stream, wsb, out);
}